// Round 12
// baseline (121.290 us; speedup 1.0000x reference)
//
#include <hip/hip_runtime.h>
#include <hip/hip_bf16.h>
#include <math.h>

#define BB   2
#define TT   2048
#define DD   768
#define HH   12
#define HD   64
#define MM   (BB*TT)
#define BTD  ((long)BB*TT*DD)

typedef __bf16 bf16x8 __attribute__((ext_vector_type(8)));
typedef __bf16 bf16x4 __attribute__((ext_vector_type(4)));
typedef float  f32x4  __attribute__((ext_vector_type(4)));

// ---------------------------------------------------------------------------
// prep: one launch for {x->bf16 (3072 blk), W4->bf16 (2304 blk),
//                       extract_rand (504 blk, 1 row/wave, bitmask scan)}
// ---------------------------------------------------------------------------
#define PREP_A 3072
#define PREP_B 2304
#define PREP_C 504

__global__ __launch_bounds__(256) void prep(
    const float* __restrict__ x,
    const float* __restrict__ w0, const float* __restrict__ w1,
    const float* __restrict__ w2, const float* __restrict__ w3,
    const void* __restrict__ maskp,
    __bf16* __restrict__ xb, __bf16* __restrict__ Wcat,
    __bf16* __restrict__ Wob, int* __restrict__ rand_idx)
{
    const int bid = blockIdx.x;
    const int tid = threadIdx.x;

    if (bid < PREP_A) {                      // x convert
        const int i = bid * 256 + tid;
        const float4 v = ((const float4*)x)[i];
        bf16x4 o;
        o.x = (__bf16)v.x; o.y = (__bf16)v.y;
        o.z = (__bf16)v.z; o.w = (__bf16)v.w;
        ((bf16x4*)xb)[i] = o;
        return;
    }
    if (bid < PREP_A + PREP_B) {             // weight convert
        const int idx = bid - PREP_A;
        const int seg = idx / 576;
        const int i = (idx % 576) * 256 + tid;
        const float* src = seg == 0 ? w0 : seg == 1 ? w1 : seg == 2 ? w2 : w3;
        __bf16* dst = seg < 3 ? Wcat + (long)seg * DD * DD : Wob;
        const float4 v = ((const float4*)src)[i];
        bf16x4 o;
        o.x = (__bf16)v.x; o.y = (__bf16)v.y;
        o.z = (__bf16)v.z; o.w = (__bf16)v.w;
        ((bf16x4*)dst)[i] = o;
        return;
    }
    // ---- extract_rand: rows 32..2047, one row per 64-lane wave ----
    {
        const int cbid = bid - PREP_A - PREP_B;
        const int wid = tid >> 6, lane = tid & 63;
        const int rsel = cbid * 4 + wid;
        if (rsel >= TT - 32) return;
        const int row = 32 + rsel;
        const unsigned char* m8 = (const unsigned char*)maskp;
        const bool u8 = (m8[1] != 0);   // mask[0][1] true: u8 -> byte1==1
        const int c0 = lane * 32;

        unsigned int bits = 0;
        if (u8) {
            const uint4* p = (const uint4*)(m8 + (long)row * TT + c0);
            const uint4 a = p[0], b = p[1];
            const unsigned int wds[8] = {a.x, a.y, a.z, a.w, b.x, b.y, b.z, b.w};
            #pragma unroll
            for (int k = 0; k < 8; k++) {
                const unsigned int w = wds[k];
                bits |= ((w       ) & 1u) << (k * 4 + 0);
                bits |= ((w >>  8 ) & 1u) << (k * 4 + 1);
                bits |= ((w >> 16 ) & 1u) << (k * 4 + 2);
                bits |= ((w >> 24 ) & 1u) << (k * 4 + 3);
            }
        } else {
            const int4* p = (const int4*)((const int*)maskp + (long)row * TT + c0);
            #pragma unroll
            for (int k = 0; k < 8; k++) {
                const int4 v = p[k];
                bits |= (v.x != 0 ? 1u : 0u) << (k * 4 + 0);
                bits |= (v.y != 0 ? 1u : 0u) << (k * 4 + 1);
                bits |= (v.z != 0 ? 1u : 0u) << (k * 4 + 2);
                bits |= (v.w != 0 ? 1u : 0u) << (k * 4 + 3);
            }
        }
        if (lane == 0) bits = 0;             // global cols c<32
        {
            const int loB = max(row - 64, c0);
            const int hiB = min(row + 64, c0 + 31);
            if (loB <= hiB) {
                const int len = hiB - loB + 1;
                const unsigned int m = (len >= 32) ? 0xFFFFFFFFu
                                                   : (((1u << len) - 1u) << (loB - c0));
                bits &= ~m;
            }
        }

        const int mcnt = __popc(bits);
        int incl = mcnt;
        #pragma unroll
        for (int d = 1; d < 64; d <<= 1) {
            const int n = __shfl_up(incl, d, 64);
            if (lane >= d) incl += n;
        }
        int pos = incl - mcnt;
        unsigned int bb = bits;
        while (bb) {
            const int t = __builtin_ctz(bb);
            bb &= bb - 1;
            if (pos < 16) rand_idx[(long)row * 16 + pos] = c0 + t;
            pos++;
        }
        const int total = __shfl(incl, 63, 64);
        if (lane == 0)
            for (int p = total; p < 16; p++) rand_idx[(long)row * 16 + p] = -1;
    }
}

// ---------------------------------------------------------------------------
// bf16 MFMA GEMM: Y = A @ B^T + bias.  2-phase double-buffered staging +
// XCD-aware block swizzle.  mode 1 also emits vT for the v head.
// ---------------------------------------------------------------------------
__global__ __launch_bounds__(256) void mfma_gemm(
    const __bf16* __restrict__ A, const __bf16* __restrict__ Bw,
    const float* __restrict__ b0, const float* __restrict__ b1,
    const float* __restrict__ b2, float* __restrict__ Y,
    __bf16* __restrict__ Yb, __bf16* __restrict__ vTout, int N, int mode)
{
    constexpr int K = DD;
    constexpr int NT = K / 32;               // 24 K-steps
    __shared__ __bf16 As[2][128 * 32];
    __shared__ __bf16 Bs[2][128 * 32];

    const int tid  = threadIdx.x;
    const int wid  = tid >> 6, lane = tid & 63;
    const int fq = lane >> 4, fr = lane & 15;
    const int wr = wid >> 1, wc = wid & 1;

    const int gx = gridDim.x;
    const int nwg = gx * gridDim.y;
    const int bid = blockIdx.y * gx + blockIdx.x;
    const int cpx = nwg >> 3;
    const int swz = (bid & 7) * cpx + (bid >> 3);
    const int m0 = (swz / gx) * 128, n0 = (swz % gx) * 128;

    f32x4 acc[4][4] = {};

    const char* Ag = (const char*)(A + (long)m0 * K);
    const char* Bg = (const char*)(Bw + (long)n0 * K);

    auto stage = [&](int buf, int k0) {
        #pragma unroll
        for (int c = 0; c < 2; c++) {
            const int o   = wid * 2048 + c * 1024 + lane * 16;
            const int row = o >> 6, kb = o & 63;
            const long goff = (long)row * (K * 2) + k0 * 2 + kb;
            __builtin_amdgcn_global_load_lds(
                (const __attribute__((address_space(1))) void*)(Ag + goff),
                (__attribute__((address_space(3))) void*)((char*)As[buf] + wid * 2048 + c * 1024),
                16, 0, 0);
            __builtin_amdgcn_global_load_lds(
                (const __attribute__((address_space(1))) void*)(Bg + goff),
                (__attribute__((address_space(3))) void*)((char*)Bs[buf] + wid * 2048 + c * 1024),
                16, 0, 0);
        }
    };

    auto compute = [&](int buf) {
        bf16x8 af[4], bfr[4];
        #pragma unroll
        for (int m = 0; m < 4; m++)
            af[m] = *(const bf16x8*)(As[buf] + ((wr * 64 + m * 16 + fr) * 32 + fq * 8));
        #pragma unroll
        for (int n = 0; n < 4; n++)
            bfr[n] = *(const bf16x8*)(Bs[buf] + ((wc * 64 + n * 16 + fr) * 32 + fq * 8));
        #pragma unroll
        for (int m = 0; m < 4; m++)
            #pragma unroll
            for (int n = 0; n < 4; n++)
                acc[m][n] = __builtin_amdgcn_mfma_f32_16x16x32_bf16(
                    af[m], bfr[n], acc[m][n], 0, 0, 0);
    };

    int cur = 0;
    stage(0, 0);
    __syncthreads();
    for (int t = 0; t < NT - 1; ++t) {
        stage(cur ^ 1, (t + 1) * 32);
        compute(cur);
        __syncthreads();
        cur ^= 1;
    }
    compute(cur);

    #pragma unroll
    for (int m = 0; m < 4; m++) {
        const int grow = m0 + wr * 64 + m * 16 + fq * 4;
        #pragma unroll
        for (int n = 0; n < 4; n++) {
            const int col = n0 + wc * 64 + n * 16 + fr;
            if (mode == 0) {
                const float bias = b0[col];
                #pragma unroll
                for (int j = 0; j < 4; j++)
                    Y[(long)(grow + j) * N + col] = acc[m][n][j] + bias;
            } else {
                const int which = col / DD;
                const int nn = col - which * DD;
                const float* bp = which == 0 ? b0 : (which == 1 ? b1 : b2);
                const float bias = bp[nn];
                const int h_ = nn >> 6, d_ = nn & 63;
                __bf16* baseb = Yb + (long)which * BTD;
                bf16x4 v4;
                #pragma unroll
                for (int j = 0; j < 4; j++) {
                    const int row = grow + j;
                    const int b_ = row >> 11, t_ = row & (TT - 1);
                    const __bf16 val = (__bf16)(acc[m][n][j] + bias);
                    baseb[(((long)b_ * HH + h_) * TT + t_) * HD + d_] = val;
                    v4[j] = val;
                }
                if (which == 2) {
                    const int b_ = grow >> 11, t0 = grow & (TT - 1);
                    *(bf16x4*)(vTout + (((long)b_ * HH + h_) * HD + d_) * TT + t0) = v4;
                }
            }
        }
    }
}

// ---------------------------------------------------------------------------
// Merged attention: blocks [0,192) dense rows 0..31, [192,1704) sparse.
// Occupancy-tuned: VGPR<=64 (launch_bounds 8 blk/CU), LDS 18.8 KB (Obuf
// aliases Pmem after PV reads), prand parked in LDS across barrier.
// No-max softmax (scores O(10)-bounded, fp32 exp overflow-safe).
// ---------------------------------------------------------------------------
#define DPROWB 512
#define PROWB 384
#define SW(r) (((r) & 7) << 4)

__global__ __launch_bounds__(256, 8) void bb_attn(
    const __bf16* __restrict__ Qb, const __bf16* __restrict__ Kb,
    const __bf16* __restrict__ Vb, const __bf16* __restrict__ vT,
    const int* __restrict__ rand_idx, float* __restrict__ part,
    __bf16* __restrict__ Ao)
{
    __shared__ __attribute__((aligned(16))) char Pmem[32 * DPROWB]; // P; then Obuf f32[32][68]
    __shared__ float lbuf[2][32], lrand[32];
    __shared__ float prl[32][16];

    const int bid = blockIdx.x;
    const int tid = threadIdx.x;
    const int w = tid >> 6, lane = tid & 63;
    const int fq = lane >> 4, fr = lane & 15;
    const int qh = w & 1, kr = w >> 1;

    if (bid < 192) {
        // ================= dense rows 0..31, flash partial =================
        const int xcd = bid & 7;
        const int idx = bid >> 3;
        const int gsel = idx >> 3;
        const int ch = idx & 7;
        const int grp = xcd + 8 * gsel;
        const int b = grp / HH, h = grp % HH;
        const int k0 = ch * 256;

        const __bf16* qbase = Qb + ((long)b * HH + h) * TT * HD;
        const __bf16* kbase = Kb + ((long)b * HH + h) * TT * HD;
        const __bf16* vTbase = vT + ((long)b * HH + h) * HD * TT;

        bf16x8 aq[2];
        #pragma unroll
        for (int kk = 0; kk < 2; kk++)
            aq[kk] = *(const bf16x8*)(qbase + (long)(qh * 16 + fr) * HD + kk * 32 + fq * 8);

        f32x4 sc[8];
        #pragma unroll
        for (int t = 0; t < 8; t++) {
            const int key = k0 + (kr * 8 + t) * 16 + fr;
            f32x4 c = {};
            #pragma unroll
            for (int kk = 0; kk < 2; kk++) {
                const bf16x8 bk = *(const bf16x8*)(kbase + (long)key * HD + kk * 32 + fq * 8);
                c = __builtin_amdgcn_mfma_f32_16x16x32_bf16(aq[kk], bk, c, 0, 0, 0);
            }
            sc[t] = c;
        }

        // exp + row-sum + P write (no max tracking)
        float lsum[4] = {};
        #pragma unroll
        for (int t = 0; t < 8; t++)
            #pragma unroll
            for (int j = 0; j < 4; j++) {
                const float p = __expf(sc[t][j] * 0.125f);
                sc[t][j] = p;
                lsum[j] += p;
            }
        #pragma unroll
        for (int o = 1; o < 16; o <<= 1)
            #pragma unroll
            for (int j = 0; j < 4; j++)
                lsum[j] += __shfl_xor(lsum[j], o, 64);
        if (fr == 0)
            #pragma unroll
            for (int j = 0; j < 4; j++)
                lbuf[kr][qh * 16 + fq * 4 + j] = lsum[j];
        #pragma unroll
        for (int t = 0; t < 8; t++) {
            const int colc = (kr * 8 + t) * 16 + fr;
            #pragma unroll
            for (int j = 0; j < 4; j++) {
                const int rl = qh * 16 + fq * 4 + j;
                *(__bf16*)(Pmem + ((rl * DPROWB + colc * 2) ^ SW(rl))) = (__bf16)sc[t][j];
            }
        }
        __syncthreads();   // b1: P + lbuf visible

        f32x4 ov[2] = {};
        {
            const int rl = qh * 16 + fr;
            #pragma unroll
            for (int t = 0; t < 8; t++) {
                const bf16x8 ap = *(const bf16x8*)(Pmem + ((rl * DPROWB + (t * 32 + fq * 8) * 2) ^ SW(rl)));
                #pragma unroll
                for (int ti = 0; ti < 2; ti++) {
                    const int d = kr * 32 + ti * 16 + fr;
                    const bf16x8 bv = *(const bf16x8*)(vTbase + (long)d * TT + k0 + t * 32 + fq * 8);
                    ov[ti] = __builtin_amdgcn_mfma_f32_16x16x32_bf16(ap, bv, ov[ti], 0, 0, 0);
                }
            }
        }
        __syncthreads();   // b2: P reads done; alias Pmem as Obuf

        float* Ob = (float*)Pmem;   // 32 x 68 fp32
        #pragma unroll
        for (int ti = 0; ti < 2; ti++)
            #pragma unroll
            for (int j = 0; j < 4; j++)
                Ob[(qh * 16 + fq * 4 + j) * 68 + kr * 32 + ti * 16 + fr] = ov[ti][j];
        __syncthreads();   // b3: Obuf visible

        {
            const int r = tid >> 3, g = tid & 7;
            float* pb = part + ((((long)b * HH + h) * 8 + ch) * 32 + r) * 66;
            if (g == 0) {
                pb[0] = 0.f;                       // no-max: m == 0 everywhere
                pb[1] = lbuf[0][r] + lbuf[1][r];
            }
            #pragma unroll
            for (int e = 0; e < 8; e++)
                pb[2 + g * 8 + e] = Ob[r * 68 + g * 8 + e];
        }
        return;
    }

    // =================== sparse rows 32..2047 ===================
    const int sbid = bid - 192;
    const int xcd = sbid & 7;
    const int idx = sbid >> 3;           // 0..188
    const int gsel = idx / 63;
    const int tq  = idx % 63;
    const int grp = xcd + 8 * gsel;
    const int b = grp / HH, h = grp % HH;
    const int q0 = (tq + 1) * 32;

    const int lo = max(32, q0 - 64);
    const int hi = min(TT - 1, q0 + 95);

    const __bf16* qbase = Qb + ((long)b * HH + h) * TT * HD;
    const __bf16* kbase = Kb + ((long)b * HH + h) * TT * HD;
    const __bf16* vbase = Vb + ((long)b * HH + h) * TT * HD;
    const __bf16* vTbase = vT + ((long)b * HH + h) * HD * TT;

    const int rr_r = tid >> 3;
    const int g = tid & 7;
    const int grow_r = q0 + rr_r;
    const int4* rrp = (const int4*)(rand_idx + (long)grow_r * 16);

    // ---- S = Q K^T (MFMA, global fragments) ----
    bf16x8 aq[2];
    #pragma unroll
    for (int kk = 0; kk < 2; kk++)
        aq[kk] = *(const bf16x8*)(qbase + (long)(q0 + qh * 16 + fr) * HD + kk * 32 + fq * 8);

    f32x4 sc[6];
    #pragma unroll
    for (int t6 = 0; t6 < 6; t6++) {
        const int colg = (kr * 6 + t6) * 16 + fr;
        const int keyg = colg < 32 ? colg : lo + colg - 32;
        const int keyc = min(keyg, TT - 1);
        f32x4 c = {};
        #pragma unroll
        for (int kk = 0; kk < 2; kk++) {
            const bf16x8 bk = *(const bf16x8*)(kbase + (long)keyc * HD + kk * 32 + fq * 8);
            c = __builtin_amdgcn_mfma_f32_16x16x32_bf16(aq[kk], bk, c, 0, 0, 0);
        }
        sc[t6] = c;
    }

    // ---- mask + scale + exp + row-sum (no max) + P write ----
    float lsum[4] = {};
    #pragma unroll
    for (int t6 = 0; t6 < 6; t6++) {
        const int colg = (kr * 6 + t6) * 16 + fr;
        const int keyg = colg < 32 ? colg : lo + colg - 32;
        #pragma unroll
        for (int j = 0; j < 4; j++) {
            const int grow = q0 + qh * 16 + fq * 4 + j;
            const int dlt = keyg - grow;
            const bool valid = (colg < 32) || (keyg <= hi && dlt <= 64 && dlt >= -64);
            const float p = valid ? __expf(sc[t6][j] * 0.125f) : 0.f;
            sc[t6][j] = p;
            lsum[j] += p;
        }
    }
    #pragma unroll
    for (int o = 1; o < 16; o <<= 1)
        #pragma unroll
        for (int j = 0; j < 4; j++)
            lsum[j] += __shfl_xor(lsum[j], o, 64);
    if (fr == 0)
        #pragma unroll
        for (int j = 0; j < 4; j++)
            lbuf[kr][qh * 16 + fq * 4 + j] = lsum[j];
    #pragma unroll
    for (int t6 = 0; t6 < 6; t6++) {
        const int key = (kr * 6 + t6) * 16 + fr;
        #pragma unroll
        for (int j = 0; j < 4; j++) {
            const int rl = qh * 16 + fq * 4 + j;
            *(__bf16*)(Pmem + ((rl * PROWB + key * 2) ^ SW(rl))) = (__bf16)sc[t6][j];
        }
    }

    // ---- rand p: batches of 4 keys, crand loaded on the fly, p -> LDS ----
    {
        const bf16x8 q8 = *(const bf16x8*)(qbase + (long)grow_r * HD + g * 8);
        float lr = 0.f;
        #pragma unroll
        for (int ch = 0; ch < 4; ch++) {
            const int4 rv = rrp[ch];
            const int cr[4] = {rv.x, rv.y, rv.z, rv.w};
            bf16x8 kf[4];
            #pragma unroll
            for (int j = 0; j < 4; j++)
                kf[j] = *(const bf16x8*)(kbase + (long)max(cr[j], 0) * HD + g * 8);
            #pragma unroll
            for (int j = 0; j < 4; j++) {
                float s = 0.f;
                #pragma unroll
                for (int e = 0; e < 8; e++) s += (float)q8[e] * (float)kf[j][e];
                s += __shfl_xor(s, 1, 64);
                s += __shfl_xor(s, 2, 64);
                s += __shfl_xor(s, 4, 64);
                const float p = (cr[j] >= 0) ? __expf(s * 0.125f) : 0.f;
                if (g == 0) prl[rr_r][ch * 4 + j] = p;
                lr += p;
            }
        }
        if (g == 0) lrand[rr_r] = lr;
    }

    __syncthreads();   // b1: P, lbuf, lrand, prl visible

    // ---- rand PV: batches of 4, p from LDS broadcast ----
    float arand[8] = {};
    #pragma unroll
    for (int ch = 0; ch < 4; ch++) {
        const int4 rv = rrp[ch];
        const int cr[4] = {rv.x, rv.y, rv.z, rv.w};
        bf16x8 vf[4];
        #pragma unroll
        for (int j = 0; j < 4; j++)
            vf[j] = *(const bf16x8*)(vbase + (long)max(cr[j], 0) * HD + g * 8);
        #pragma unroll
        for (int j = 0; j < 4; j++) {
            const float p = prl[rr_r][ch * 4 + j];
            #pragma unroll
            for (int e = 0; e < 8; e++) arand[e] += p * (float)vf[j][e];
        }
    }

    // ---- O = P V : MFMA, P from LDS, V^T fragments from global ----
    f32x4 ov[2] = {};
    {
        const int rl = qh * 16 + fr;
        #pragma unroll
        for (int t = 0; t < 6; t++) {
            const bf16x8 ap = *(const bf16x8*)(Pmem + ((rl * PROWB + (t * 32 + fq * 8) * 2) ^ SW(rl)));
            const int key0 = t * 32 + fq * 8;
            int tg = key0 < 32 ? key0 : lo + key0 - 32;
            tg = min(tg, TT - 8);
            #pragma unroll
            for (int ti = 0; ti < 2; ti++) {
                const int d = kr * 32 + ti * 16 + fr;
                const bf16x8 bv = *(const bf16x8*)(vTbase + (long)d * TT + tg);
                ov[ti] = __builtin_amdgcn_mfma_f32_16x16x32_bf16(ap, bv, ov[ti], 0, 0, 0);
            }
        }
    }
    __syncthreads();   // b2: P reads done; alias Pmem as Obuf

    float* Ob = (float*)Pmem;   // 32 x 68 fp32
    #pragma unroll
    for (int ti = 0; ti < 2; ti++)
        #pragma unroll
        for (int j = 0; j < 4; j++)
            Ob[(qh * 16 + fq * 4 + j) * 68 + kr * 32 + ti * 16 + fr] = ov[ti][j];

    __syncthreads();   // b3: Obuf visible

    {
        const float linv = 1.f /
            (lbuf[0][rr_r] + lbuf[1][rr_r] + lrand[rr_r]);
        bf16x8 o8;
        #pragma unroll
        for (int e = 0; e < 8; e++)
            o8[e] = (__bf16)((Ob[rr_r * 68 + g * 8 + e] + arand[e]) * linv);
        *(bf16x8*)(Ao + ((long)b * TT + grow_r) * DD + h * HD + g * 8) = o8;
    }
}

__global__ __launch_bounds__(256) void bb_dense_combine(
    const float* __restrict__ part, __bf16* __restrict__ Ao)
{
    const int h = blockIdx.x, b = blockIdx.y;
    const int tid = threadIdx.x;
    const int r = tid >> 3, dsl = (tid & 7) * 8;
    const float* pb = part + (((long)b * HH + h) * 8 * 32 + r) * 66;
    float M = -INFINITY;
    #pragma unroll
    for (int c = 0; c < 8; c++) M = fmaxf(M, pb[(long)c * 32 * 66]);
    float L = 0.f, o[8] = {};
    #pragma unroll
    for (int c = 0; c < 8; c++) {
        const float* pc = pb + (long)c * 32 * 66;
        const float w = __expf(pc[0] - M);
        L += w * pc[1];
        #pragma unroll
        for (int j = 0; j < 8; j++) o[j] += w * pc[2 + dsl + j];
    }
    const float inv = 1.f / L;
    const long ob = ((long)b * TT + r) * DD + h * HD + dsl;
    #pragma unroll
    for (int j = 0; j < 8; j++) Ao[ob + j] = (__bf16)(o[j] * inv);
}

// ---------------------------------------------------------------------------
extern "C" void kernel_launch(void* const* d_in, const int* in_sizes, int n_in,
                              void* d_out, int out_size, void* d_ws, size_t ws_size,
                              hipStream_t stream)
{
    const float* x  = (const float*)d_in[0];
    const float* Wq = (const float*)d_in[1];
    const float* bq = (const float*)d_in[2];
    const float* Wk = (const float*)d_in[3];
    const float* bk = (const float*)d_in[4];
    const float* Wv = (const float*)d_in[5];
    const float* bv = (const float*)d_in[6];
    const float* Wo = (const float*)d_in[7];
    const float* bo = (const float*)d_in[8];
    const void*  mask = d_in[9];

    __bf16* xb   = (__bf16*)d_ws;
    __bf16* qkvb = xb + BTD;
    __bf16* vTb  = qkvb + 3 * BTD;
    __bf16* aob  = vTb + BTD;
    __bf16* Wcat = aob + BTD;
    __bf16* Wob  = Wcat + (long)3 * DD * DD;
    int*    rand_idx = (int*)(Wob + (long)DD * DD);
    float*  part = (float*)(rand_idx + (long)TT * 16);

    prep<<<PREP_A + PREP_B + PREP_C, 256, 0, stream>>>(
        x, Wq, Wk, Wv, Wo, mask, xb, Wcat, Wob, rand_idx);

    mfma_gemm<<<dim3(3 * DD / 128, MM / 128), 256, 0, stream>>>(
        xb, Wcat, bq, bk, bv, nullptr, qkvb, vTb, 3 * DD, 1);

    bb_attn<<<192 + 1512, 256, 0, stream>>>(
        qkvb, qkvb + BTD, qkvb + 2 * BTD, vTb, rand_idx, part, aob);

    bb_dense_combine<<<dim3(HH, BB), 256, 0, stream>>>(part, aob);

    mfma_gemm<<<dim3(DD / 128, MM / 128), 256, 0, stream>>>(
        aob, Wob, bo, bo, bo, (float*)d_out, nullptr, nullptr, DD, 0);
}

// Round 13
// 101.736 us; speedup vs baseline: 1.1922x; 1.1922x over previous
//
#include <hip/hip_runtime.h>
#include <hip/hip_bf16.h>
#include <math.h>

#define BB   2
#define TT   2048
#define DD   768
#define HH   12
#define HD   64
#define MM   (BB*TT)
#define BTD  ((long)BB*TT*DD)

typedef __bf16 bf16x8 __attribute__((ext_vector_type(8)));
typedef __bf16 bf16x4 __attribute__((ext_vector_type(4)));
typedef float  f32x4  __attribute__((ext_vector_type(4)));

// ---------------------------------------------------------------------------
// prep: one launch for {W4->bf16 (2304 blk), extract_rand (504 blk)}
// (x->bf16 is fused into the QKV GEMM's A staging)
// ---------------------------------------------------------------------------
#define PREP_B 2304
#define PREP_C 504

__global__ __launch_bounds__(256) void prep(
    const float* __restrict__ w0, const float* __restrict__ w1,
    const float* __restrict__ w2, const float* __restrict__ w3,
    const void* __restrict__ maskp,
    __bf16* __restrict__ Wcat, __bf16* __restrict__ Wob,
    int* __restrict__ rand_idx)
{
    const int bid = blockIdx.x;
    const int tid = threadIdx.x;

    if (bid < PREP_B) {                      // weight convert
        const int seg = bid / 576;
        const int i = (bid % 576) * 256 + tid;
        const float* src = seg == 0 ? w0 : seg == 1 ? w1 : seg == 2 ? w2 : w3;
        __bf16* dst = seg < 3 ? Wcat + (long)seg * DD * DD : Wob;
        const float4 v = ((const float4*)src)[i];
        bf16x4 o;
        o.x = (__bf16)v.x; o.y = (__bf16)v.y;
        o.z = (__bf16)v.z; o.w = (__bf16)v.w;
        ((bf16x4*)dst)[i] = o;
        return;
    }
    // ---- extract_rand: rows 32..2047, one row per 64-lane wave ----
    {
        const int cbid = bid - PREP_B;
        const int wid = tid >> 6, lane = tid & 63;
        const int rsel = cbid * 4 + wid;
        if (rsel >= TT - 32) return;
        const int row = 32 + rsel;
        const unsigned char* m8 = (const unsigned char*)maskp;
        const bool u8 = (m8[1] != 0);   // mask[0][1] true: u8 -> byte1==1
        const int c0 = lane * 32;

        unsigned int bits = 0;
        if (u8) {
            const uint4* p = (const uint4*)(m8 + (long)row * TT + c0);
            const uint4 a = p[0], b = p[1];
            const unsigned int wds[8] = {a.x, a.y, a.z, a.w, b.x, b.y, b.z, b.w};
            #pragma unroll
            for (int k = 0; k < 8; k++) {
                const unsigned int w = wds[k];
                bits |= ((w       ) & 1u) << (k * 4 + 0);
                bits |= ((w >>  8 ) & 1u) << (k * 4 + 1);
                bits |= ((w >> 16 ) & 1u) << (k * 4 + 2);
                bits |= ((w >> 24 ) & 1u) << (k * 4 + 3);
            }
        } else {
            const int4* p = (const int4*)((const int*)maskp + (long)row * TT + c0);
            #pragma unroll
            for (int k = 0; k < 8; k++) {
                const int4 v = p[k];
                bits |= (v.x != 0 ? 1u : 0u) << (k * 4 + 0);
                bits |= (v.y != 0 ? 1u : 0u) << (k * 4 + 1);
                bits |= (v.z != 0 ? 1u : 0u) << (k * 4 + 2);
                bits |= (v.w != 0 ? 1u : 0u) << (k * 4 + 3);
            }
        }
        if (lane == 0) bits = 0;             // global cols c<32
        {
            const int loB = max(row - 64, c0);
            const int hiB = min(row + 64, c0 + 31);
            if (loB <= hiB) {
                const int len = hiB - loB + 1;
                const unsigned int m = (len >= 32) ? 0xFFFFFFFFu
                                                   : (((1u << len) - 1u) << (loB - c0));
                bits &= ~m;
            }
        }

        const int mcnt = __popc(bits);
        int incl = mcnt;
        #pragma unroll
        for (int d = 1; d < 64; d <<= 1) {
            const int n = __shfl_up(incl, d, 64);
            if (lane >= d) incl += n;
        }
        int pos = incl - mcnt;
        unsigned int bb = bits;
        while (bb) {
            const int t = __builtin_ctz(bb);
            bb &= bb - 1;
            if (pos < 16) rand_idx[(long)row * 16 + pos] = c0 + t;
            pos++;
        }
        const int total = __shfl(incl, 63, 64);
        if (lane == 0)
            for (int p = total; p < 16; p++) rand_idx[(long)row * 16 + p] = -1;
    }
}

// ---------------------------------------------------------------------------
// bf16 MFMA GEMM: Y = A @ B^T + bias.  2-phase double-buffered staging +
// XCD-aware block swizzle.
//   MODE 0: A bf16 (global_load_lds), fp32 Y row-major (N=768)
//   MODE 1: A fp32 (reg-staged cvt->LDS), N=2304 -> bf16 q|k|v + vT
// ---------------------------------------------------------------------------
template<int MODE>
__global__ __launch_bounds__(256) void mfma_gemm(
    const __bf16* __restrict__ A, const float* __restrict__ Af32,
    const __bf16* __restrict__ Bw,
    const float* __restrict__ b0, const float* __restrict__ b1,
    const float* __restrict__ b2, float* __restrict__ Y,
    __bf16* __restrict__ Yb, __bf16* __restrict__ vTout, int N)
{
    constexpr int K = DD;
    constexpr int NT = K / 32;               // 24 K-steps
    __shared__ __bf16 As[2][128 * 32];
    __shared__ __bf16 Bs[2][128 * 32];

    const int tid  = threadIdx.x;
    const int wid  = tid >> 6, lane = tid & 63;
    const int fq = lane >> 4, fr = lane & 15;
    const int wr = wid >> 1, wc = wid & 1;

    const int gx = gridDim.x;
    const int nwg = gx * gridDim.y;
    const int bid = blockIdx.y * gx + blockIdx.x;
    const int cpx = nwg >> 3;
    const int swz = (bid & 7) * cpx + (bid >> 3);
    const int m0 = (swz / gx) * 128, n0 = (swz % gx) * 128;

    f32x4 acc[4][4] = {};

    const char* Ag = (const char*)(A + (long)m0 * K);
    const float* Af = Af32 + (long)m0 * K;
    const char* Bg = (const char*)(Bw + (long)n0 * K);

    f32x4 ar[4];   // MODE 1: in-flight fp32 A fragments

    auto stageB = [&](int buf, int k0) {
        #pragma unroll
        for (int c = 0; c < 2; c++) {
            const int o   = wid * 2048 + c * 1024 + lane * 16;
            const int row = o >> 6, kb = o & 63;
            const long goff = (long)row * (K * 2) + k0 * 2 + kb;
            __builtin_amdgcn_global_load_lds(
                (const __attribute__((address_space(1))) void*)(Bg + goff),
                (__attribute__((address_space(3))) void*)((char*)Bs[buf] + wid * 2048 + c * 1024),
                16, 0, 0);
        }
    };
    auto stageA_lds = [&](int buf, int k0) {   // MODE 0
        #pragma unroll
        for (int c = 0; c < 2; c++) {
            const int o   = wid * 2048 + c * 1024 + lane * 16;
            const int row = o >> 6, kb = o & 63;
            const long goff = (long)row * (K * 2) + k0 * 2 + kb;
            __builtin_amdgcn_global_load_lds(
                (const __attribute__((address_space(1))) void*)(Ag + goff),
                (__attribute__((address_space(3))) void*)((char*)As[buf] + wid * 2048 + c * 1024),
                16, 0, 0);
        }
    };
    auto loadA_f32 = [&](int k0) {             // MODE 1: issue loads
        #pragma unroll
        for (int c = 0; c < 2; c++) {
            const int o   = wid * 2048 + c * 1024 + lane * 16;  // bf16 byte off
            const int row = o >> 6, kb = o & 63;
            const float* p = Af + (long)row * K + k0 + (kb >> 1);
            ar[c * 2 + 0] = *(const f32x4*)(p);
            ar[c * 2 + 1] = *(const f32x4*)(p + 4);
        }
    };
    auto writeA_f32 = [&](int buf) {           // MODE 1: cvt + LDS write
        #pragma unroll
        for (int c = 0; c < 2; c++) {
            const int o = wid * 2048 + c * 1024 + lane * 16;
            bf16x8 v;
            #pragma unroll
            for (int e = 0; e < 4; e++) {
                v[e]     = (__bf16)ar[c * 2][e];
                v[e + 4] = (__bf16)ar[c * 2 + 1][e];
            }
            *(bf16x8*)((char*)As[buf] + o) = v;
        }
    };

    auto compute = [&](int buf) {
        bf16x8 af[4], bfr[4];
        #pragma unroll
        for (int m = 0; m < 4; m++)
            af[m] = *(const bf16x8*)(As[buf] + ((wr * 64 + m * 16 + fr) * 32 + fq * 8));
        #pragma unroll
        for (int n = 0; n < 4; n++)
            bfr[n] = *(const bf16x8*)(Bs[buf] + ((wc * 64 + n * 16 + fr) * 32 + fq * 8));
        #pragma unroll
        for (int m = 0; m < 4; m++)
            #pragma unroll
            for (int n = 0; n < 4; n++)
                acc[m][n] = __builtin_amdgcn_mfma_f32_16x16x32_bf16(
                    af[m], bfr[n], acc[m][n], 0, 0, 0);
    };

    int cur = 0;
    if (MODE == 1) { loadA_f32(0); stageB(0, 0); writeA_f32(0); }
    else           { stageA_lds(0, 0); stageB(0, 0); }
    __syncthreads();
    for (int t = 0; t < NT - 1; ++t) {
        if (MODE == 1) { loadA_f32((t + 1) * 32); stageB(cur ^ 1, (t + 1) * 32); }
        else           { stageA_lds(cur ^ 1, (t + 1) * 32); stageB(cur ^ 1, (t + 1) * 32); }
        compute(cur);
        if (MODE == 1) writeA_f32(cur ^ 1);
        __syncthreads();
        cur ^= 1;
    }
    compute(cur);

    #pragma unroll
    for (int m = 0; m < 4; m++) {
        const int grow = m0 + wr * 64 + m * 16 + fq * 4;
        #pragma unroll
        for (int n = 0; n < 4; n++) {
            const int col = n0 + wc * 64 + n * 16 + fr;
            if (MODE == 0) {
                const float bias = b0[col];
                #pragma unroll
                for (int j = 0; j < 4; j++)
                    Y[(long)(grow + j) * N + col] = acc[m][n][j] + bias;
            } else {
                const int which = col / DD;
                const int nn = col - which * DD;
                const float* bp = which == 0 ? b0 : (which == 1 ? b1 : b2);
                const float bias = bp[nn];
                const int h_ = nn >> 6, d_ = nn & 63;
                __bf16* baseb = Yb + (long)which * BTD;
                bf16x4 v4;
                #pragma unroll
                for (int j = 0; j < 4; j++) {
                    const int row = grow + j;
                    const int b_ = row >> 11, t_ = row & (TT - 1);
                    const __bf16 val = (__bf16)(acc[m][n][j] + bias);
                    baseb[(((long)b_ * HH + h_) * TT + t_) * HD + d_] = val;
                    v4[j] = val;
                }
                if (which == 2) {
                    const int b_ = grow >> 11, t0 = grow & (TT - 1);
                    *(bf16x4*)(vTout + (((long)b_ * HH + h_) * HD + d_) * TT + t0) = v4;
                }
            }
        }
    }
}

// ---------------------------------------------------------------------------
// Merged attention (r11 verbatim): blocks [0,192) dense, [192,1704) sparse.
// No-max softmax; 2 barriers sparse path; VGPR ~88, no launch_bounds cap.
// ---------------------------------------------------------------------------
#define DPROWB 512
#define PROWB 384
#define SW(r) (((r) & 7) << 4)

__global__ __launch_bounds__(256) void bb_attn(
    const __bf16* __restrict__ Qb, const __bf16* __restrict__ Kb,
    const __bf16* __restrict__ Vb, const __bf16* __restrict__ vT,
    const int* __restrict__ rand_idx, float* __restrict__ part,
    __bf16* __restrict__ Ao)
{
    __shared__ __attribute__((aligned(16))) char Pmem[32 * DPROWB];
    __shared__ float Obuf[32][68];
    __shared__ float lbuf[2][32], lrand[32];

    const int bid = blockIdx.x;
    const int tid = threadIdx.x;
    const int w = tid >> 6, lane = tid & 63;
    const int fq = lane >> 4, fr = lane & 15;
    const int qh = w & 1, kr = w >> 1;

    if (bid < 192) {
        const int xcd = bid & 7;
        const int idx = bid >> 3;
        const int gsel = idx >> 3;
        const int ch = idx & 7;
        const int grp = xcd + 8 * gsel;
        const int b = grp / HH, h = grp % HH;
        const int k0 = ch * 256;

        const __bf16* qbase = Qb + ((long)b * HH + h) * TT * HD;
        const __bf16* kbase = Kb + ((long)b * HH + h) * TT * HD;
        const __bf16* vTbase = vT + ((long)b * HH + h) * HD * TT;

        bf16x8 aq[2];
        #pragma unroll
        for (int kk = 0; kk < 2; kk++)
            aq[kk] = *(const bf16x8*)(qbase + (long)(qh * 16 + fr) * HD + kk * 32 + fq * 8);

        f32x4 sc[8];
        #pragma unroll
        for (int t = 0; t < 8; t++) {
            const int key = k0 + (kr * 8 + t) * 16 + fr;
            f32x4 c = {};
            #pragma unroll
            for (int kk = 0; kk < 2; kk++) {
                const bf16x8 bk = *(const bf16x8*)(kbase + (long)key * HD + kk * 32 + fq * 8);
                c = __builtin_amdgcn_mfma_f32_16x16x32_bf16(aq[kk], bk, c, 0, 0, 0);
            }
            sc[t] = c;
        }

        float lsum[4] = {};
        #pragma unroll
        for (int t = 0; t < 8; t++)
            #pragma unroll
            for (int j = 0; j < 4; j++) {
                const float p = __expf(sc[t][j] * 0.125f);
                sc[t][j] = p;
                lsum[j] += p;
            }
        #pragma unroll
        for (int o = 1; o < 16; o <<= 1)
            #pragma unroll
            for (int j = 0; j < 4; j++)
                lsum[j] += __shfl_xor(lsum[j], o, 64);
        if (fr == 0)
            #pragma unroll
            for (int j = 0; j < 4; j++)
                lbuf[kr][qh * 16 + fq * 4 + j] = lsum[j];
        #pragma unroll
        for (int t = 0; t < 8; t++) {
            const int colc = (kr * 8 + t) * 16 + fr;
            #pragma unroll
            for (int j = 0; j < 4; j++) {
                const int rl = qh * 16 + fq * 4 + j;
                *(__bf16*)(Pmem + ((rl * DPROWB + colc * 2) ^ SW(rl))) = (__bf16)sc[t][j];
            }
        }
        __syncthreads();   // barrier 1: P + lbuf visible

        f32x4 ov[2] = {};
        {
            const int rl = qh * 16 + fr;
            #pragma unroll
            for (int t = 0; t < 8; t++) {
                const bf16x8 ap = *(const bf16x8*)(Pmem + ((rl * DPROWB + (t * 32 + fq * 8) * 2) ^ SW(rl)));
                #pragma unroll
                for (int ti = 0; ti < 2; ti++) {
                    const int d = kr * 32 + ti * 16 + fr;
                    const bf16x8 bv = *(const bf16x8*)(vTbase + (long)d * TT + k0 + t * 32 + fq * 8);
                    ov[ti] = __builtin_amdgcn_mfma_f32_16x16x32_bf16(ap, bv, ov[ti], 0, 0, 0);
                }
            }
        }

        #pragma unroll
        for (int ti = 0; ti < 2; ti++)
            #pragma unroll
            for (int j = 0; j < 4; j++)
                Obuf[qh * 16 + fq * 4 + j][kr * 32 + ti * 16 + fr] = ov[ti][j];
        __syncthreads();   // barrier 2: Obuf visible

        {
            const int r = tid >> 3, g = tid & 7;
            float* pb = part + ((((long)b * HH + h) * 8 + ch) * 32 + r) * 66;
            if (g == 0) {
                pb[0] = 0.f;                       // no-max: m == 0 everywhere
                pb[1] = lbuf[0][r] + lbuf[1][r];
            }
            #pragma unroll
            for (int e = 0; e < 8; e++)
                pb[2 + g * 8 + e] = Obuf[r][g * 8 + e];
        }
        return;
    }

    // =================== sparse rows 32..2047 ===================
    const int sbid = bid - 192;
    const int xcd = sbid & 7;
    const int idx = sbid >> 3;           // 0..188
    const int gsel = idx / 63;
    const int tq  = idx % 63;
    const int grp = xcd + 8 * gsel;
    const int b = grp / HH, h = grp % HH;
    const int q0 = (tq + 1) * 32;

    const int lo = max(32, q0 - 64);
    const int hi = min(TT - 1, q0 + 95);

    const __bf16* qbase = Qb + ((long)b * HH + h) * TT * HD;
    const __bf16* kbase = Kb + ((long)b * HH + h) * TT * HD;
    const __bf16* vbase = Vb + ((long)b * HH + h) * TT * HD;
    const __bf16* vTbase = vT + ((long)b * HH + h) * HD * TT;

    const int rr_r = tid >> 3;
    const int g = tid & 7;
    const int grow_r = q0 + rr_r;
    int crand[16];
    {
        const int4* rrv = (const int4*)(rand_idx + (long)grow_r * 16);
        #pragma unroll
        for (int c4 = 0; c4 < 4; c4++) {
            const int4 rv = rrv[c4];
            crand[c4 * 4 + 0] = rv.x; crand[c4 * 4 + 1] = rv.y;
            crand[c4 * 4 + 2] = rv.z; crand[c4 * 4 + 3] = rv.w;
        }
    }

    // ---- S = Q K^T (MFMA, global fragments) ----
    bf16x8 aq[2];
    #pragma unroll
    for (int kk = 0; kk < 2; kk++)
        aq[kk] = *(const bf16x8*)(qbase + (long)(q0 + qh * 16 + fr) * HD + kk * 32 + fq * 8);

    f32x4 sc[6];
    #pragma unroll
    for (int t6 = 0; t6 < 6; t6++) {
        const int colg = (kr * 6 + t6) * 16 + fr;
        const int keyg = colg < 32 ? colg : lo + colg - 32;
        const int keyc = min(keyg, TT - 1);
        f32x4 c = {};
        #pragma unroll
        for (int kk = 0; kk < 2; kk++) {
            const bf16x8 bk = *(const bf16x8*)(kbase + (long)keyc * HD + kk * 32 + fq * 8);
            c = __builtin_amdgcn_mfma_f32_16x16x32_bf16(aq[kk], bk, c, 0, 0, 0);
        }
        sc[t6] = c;
    }

    // ---- mask + scale + exp + row-sum (no max) + P write ----
    float lsum[4] = {};
    #pragma unroll
    for (int t6 = 0; t6 < 6; t6++) {
        const int colg = (kr * 6 + t6) * 16 + fr;
        const int keyg = colg < 32 ? colg : lo + colg - 32;
        #pragma unroll
        for (int j = 0; j < 4; j++) {
            const int grow = q0 + qh * 16 + fq * 4 + j;
            const int dlt = keyg - grow;
            const bool valid = (colg < 32) || (keyg <= hi && dlt <= 64 && dlt >= -64);
            const float p = valid ? __expf(sc[t6][j] * 0.125f) : 0.f;
            sc[t6][j] = p;
            lsum[j] += p;
        }
    }
    #pragma unroll
    for (int o = 1; o < 16; o <<= 1)
        #pragma unroll
        for (int j = 0; j < 4; j++)
            lsum[j] += __shfl_xor(lsum[j], o, 64);
    if (fr == 0)
        #pragma unroll
        for (int j = 0; j < 4; j++)
            lbuf[kr][qh * 16 + fq * 4 + j] = lsum[j];
    #pragma unroll
    for (int t6 = 0; t6 < 6; t6++) {
        const int key = (kr * 6 + t6) * 16 + fr;
        #pragma unroll
        for (int j = 0; j < 4; j++) {
            const int rl = qh * 16 + fq * 4 + j;
            *(__bf16*)(Pmem + ((rl * PROWB + key * 2) ^ SW(rl))) = (__bf16)sc[t6][j];
        }
    }

    // ---- rand scores (coalesced group loads) + early V prefetch ----
    const bf16x8 q8 = *(const bf16x8*)(qbase + (long)grow_r * HD + g * 8);
    float srand[16];
    bf16x8 vf0[8];
    #pragma unroll
    for (int j = 0; j < 8; j++)
        vf0[j] = *(const bf16x8*)(vbase + (long)max(crand[j], 0) * HD + g * 8);
    #pragma unroll
    for (int ch = 0; ch < 2; ch++) {
        bf16x8 kf[8];
        #pragma unroll
        for (int j = 0; j < 8; j++)
            kf[j] = *(const bf16x8*)(kbase + (long)max(crand[ch * 8 + j], 0) * HD + g * 8);
        #pragma unroll
        for (int j = 0; j < 8; j++) {
            float s = 0.f;
            #pragma unroll
            for (int e = 0; e < 8; e++) s += (float)q8[e] * (float)kf[j][e];
            s += __shfl_xor(s, 1, 64);
            s += __shfl_xor(s, 2, 64);
            s += __shfl_xor(s, 4, 64);
            srand[ch * 8 + j] = crand[ch * 8 + j] >= 0 ? s * 0.125f : -INFINITY;
        }
    }
    float prand[16];
    {
        float lr = 0.f;
        #pragma unroll
        for (int j = 0; j < 16; j++) {
            prand[j] = __expf(srand[j]);     // exp(-inf) = 0 for pads
            lr += prand[j];
        }
        if (g == 0) lrand[rr_r] = lr;
    }

    __syncthreads();   // barrier 1: P, lbuf, lrand visible

    // ---- rand PV: second-half V loads issued first, then multiply ----
    float arand[8] = {};
    {
        bf16x8 vf1[8];
        #pragma unroll
        for (int j = 0; j < 8; j++)
            vf1[j] = *(const bf16x8*)(vbase + (long)max(crand[8 + j], 0) * HD + g * 8);
        #pragma unroll
        for (int j = 0; j < 8; j++) {
            const float p = prand[j];
            #pragma unroll
            for (int e = 0; e < 8; e++) arand[e] += p * (float)vf0[j][e];
        }
        #pragma unroll
        for (int j = 0; j < 8; j++) {
            const float p = prand[8 + j];
            #pragma unroll
            for (int e = 0; e < 8; e++) arand[e] += p * (float)vf1[j][e];
        }
    }

    // ---- O = P V : MFMA, P from LDS, V^T fragments from global ----
    f32x4 ov[2] = {};
    {
        const int rl = qh * 16 + fr;
        #pragma unroll
        for (int t = 0; t < 6; t++) {
            const bf16x8 ap = *(const bf16x8*)(Pmem + ((rl * PROWB + (t * 32 + fq * 8) * 2) ^ SW(rl)));
            const int key0 = t * 32 + fq * 8;
            int tg = key0 < 32 ? key0 : lo + key0 - 32;
            tg = min(tg, TT - 8);
            #pragma unroll
            for (int ti = 0; ti < 2; ti++) {
                const int d = kr * 32 + ti * 16 + fr;
                const bf16x8 bv = *(const bf16x8*)(vTbase + (long)d * TT + tg);
                ov[ti] = __builtin_amdgcn_mfma_f32_16x16x32_bf16(ap, bv, ov[ti], 0, 0, 0);
            }
        }
    }

    #pragma unroll
    for (int ti = 0; ti < 2; ti++)
        #pragma unroll
        for (int j = 0; j < 4; j++)
            Obuf[qh * 16 + fq * 4 + j][kr * 32 + ti * 16 + fr] = ov[ti][j];

    __syncthreads();   // barrier 2: Obuf visible

    {
        const float linv = 1.f /
            (lbuf[0][rr_r] + lbuf[1][rr_r] + lrand[rr_r]);
        bf16x8 o8;
        #pragma unroll
        for (int e = 0; e < 8; e++)
            o8[e] = (__bf16)((Obuf[rr_r][g * 8 + e] + arand[e]) * linv);
        *(bf16x8*)(Ao + ((long)b * TT + grow_r) * DD + h * HD + g * 8) = o8;
    }
}

__global__ __launch_bounds__(256) void bb_dense_combine(
    const float* __restrict__ part, __bf16* __restrict__ Ao)
{
    const int h = blockIdx.x, b = blockIdx.y;
    const int tid = threadIdx.x;
    const int r = tid >> 3, dsl = (tid & 7) * 8;
    const float* pb = part + (((long)b * HH + h) * 8 * 32 + r) * 66;
    float M = -INFINITY;
    #pragma unroll
    for (int c = 0; c < 8; c++) M = fmaxf(M, pb[(long)c * 32 * 66]);
    float L = 0.f, o[8] = {};
    #pragma unroll
    for (int c = 0; c < 8; c++) {
        const float* pc = pb + (long)c * 32 * 66;
        const float w = __expf(pc[0] - M);
        L += w * pc[1];
        #pragma unroll
        for (int j = 0; j < 8; j++) o[j] += w * pc[2 + dsl + j];
    }
    const float inv = 1.f / L;
    const long ob = ((long)b * TT + r) * DD + h * HD + dsl;
    #pragma unroll
    for (int j = 0; j < 8; j++) Ao[ob + j] = (__bf16)(o[j] * inv);
}

// ---------------------------------------------------------------------------
extern "C" void kernel_launch(void* const* d_in, const int* in_sizes, int n_in,
                              void* d_out, int out_size, void* d_ws, size_t ws_size,
                              hipStream_t stream)
{
    const float* x  = (const float*)d_in[0];
    const float* Wq = (const float*)d_in[1];
    const float* bq = (const float*)d_in[2];
    const float* Wk = (const float*)d_in[3];
    const float* bk = (const float*)d_in[4];
    const float* Wv = (const float*)d_in[5];
    const float* bv = (const float*)d_in[6];
    const float* Wo = (const float*)d_in[7];
    const float* bo = (const float*)d_in[8];
    const void*  mask = d_in[9];

    __bf16* qkvb = (__bf16*)d_ws;             // q|k|v bf16, 3*BTD
    __bf16* vTb  = qkvb + 3 * BTD;
    __bf16* aob  = vTb + BTD;
    __bf16* Wcat = aob + BTD;
    __bf16* Wob  = Wcat + (long)3 * DD * DD;
    int*    rand_idx = (int*)(Wob + (long)DD * DD);
    float*  part = (float*)(rand_idx + (long)TT * 16);

    prep<<<PREP_B + PREP_C, 256, 0, stream>>>(
        Wq, Wk, Wv, Wo, mask, Wcat, Wob, rand_idx);

    mfma_gemm<1><<<dim3(3 * DD / 128, MM / 128), 256, 0, stream>>>(
        nullptr, x, Wcat, bq, bk, bv, nullptr, qkvb, vTb, 3 * DD);

    bb_attn<<<192 + 1512, 256, 0, stream>>>(
        qkvb, qkvb + BTD, qkvb + 2 * BTD, vTb, rand_idx, part, aob);

    bb_dense_combine<<<dim3(HH, BB), 256, 0, stream>>>(part, aob);

    mfma_gemm<0><<<dim3(DD / 128, MM / 128), 256, 0, stream>>>(
        aob, nullptr, Wob, bo, bo, bo, (float*)d_out, nullptr, nullptr, DD);
}